// Round 3
// baseline (92.810 us; speedup 1.0000x reference)
//
#include <hip/hip_runtime.h>
#include <math.h>

#define BB 64
#define SQ 32
#define SD 256
#define HH 128
#define NQ (BB*SQ)   // 2048
#define ND (BB*SD)   // 16384
#define AG 8         // a's per scores block
#define DCHUNK 32    // d rows per prep block
#define QCHUNK 4     // q rows per prep block
#define NBLK 512     // uniform prep grid: 512 blocks x (32 d + 4 q) rows
#define PARTS 8      // partials per batch (d: 256/32, q: 32/4)

using short8  = __attribute__((ext_vector_type(8))) short;
using floatx4 = __attribute__((ext_vector_type(4))) float;

__device__ inline unsigned short f2bf(float x) {
  union { float f; unsigned u; } c; c.f = x;
  unsigned r = c.u + 0x7fffu + ((c.u >> 16) & 1u);  // RNE
  return (unsigned short)(r >> 16);
}

// ---------------------------------------------------------------------------
// Kernel 1 (uniform 512 blocks, no tail wave): block bid preps
//   - d-chunk bid: 32 rows -> dng, dcol[bid][128], da2[bid]
//   - q-chunk bid:  4 rows -> qng, qcol[bid][128], qa2[bid]
// (was 576 blocks = 2 full dispatch waves + a 64-block tail; now exactly
//  2 blocks/CU, 36 rows each). All avg* combining moved to kernel 2.
// Block 0 zeroes the completion counter for kernel 2's last-block CE.
// ---------------------------------------------------------------------------
__global__ __launch_bounds__(256) void prep_kernel(
    const float* __restrict__ qe, const float* __restrict__ de,
    const int* __restrict__ qmask, const int* __restrict__ dmask,
    unsigned short* __restrict__ qng, unsigned short* __restrict__ dng,
    float* __restrict__ dcol, float* __restrict__ da2,
    float* __restrict__ qcol, float* __restrict__ qa2,
    unsigned int* __restrict__ cnt) {
  __shared__ float colsum[8 * 128];    // d col partials [group][col]
  __shared__ float colsumQ[4 * 128];   // q col partials [group<4][col]
  __shared__ float redD[4], redQ[4];
  const int bid = blockIdx.x, tid = threadIdx.x;
  const int g = tid >> 5, c = tid & 31, wave = tid >> 6;

  if (bid == 0 && tid == 0) *cnt = 0;   // re-poisoned each iter; re-arm

  // ---- d chunk: rows {g, g+8, g+16, g+24}, prefetched ----
  const float* dsrc = de + (size_t)bid * DCHUNK * HH;
  const int*  dmk  = dmask + bid * DCHUNK;
  unsigned short* ddst = dng + (size_t)bid * DCHUNK * HH;
  float4 v[4];
#pragma unroll
  for (int i = 0; i < 4; i++)
    v[i] = ((const float4*)(dsrc + (size_t)(g + 8 * i) * HH))[c];
  int m[4];
#pragma unroll
  for (int i = 0; i < 4; i++) m[i] = dmk[g + 8 * i];

  // ---- q chunk: groups 0-3 take one row each (row = bid*4+g) ----
  float4 vq; int mq = 0;
  if (g < 4) {
    vq = ((const float4*)(qe + (size_t)(bid * QCHUNK + g) * HH))[c];
    mq = qmask[bid * QCHUNK + g];
  }

  float cs0 = 0.f, cs1 = 0.f, cs2 = 0.f, cs3 = 0.f;  // d per-col partials
  float a2 = 0.f;                                    // d partial sum ||n||^2
#pragma unroll
  for (int i = 0; i < 4; i++) {
    float ss = v[i].x*v[i].x + v[i].y*v[i].y + v[i].z*v[i].z + v[i].w*v[i].w;
#pragma unroll
    for (int off = 16; off; off >>= 1) ss += __shfl_xor(ss, off);  // 32-lane group
    float inv = 1.0f / fmaxf(sqrtf(ss), 1e-12f);
    float nx = v[i].x * inv, ny = v[i].y * inv, nz = v[i].z * inv, nw = v[i].w * inv;
    cs0 += nx; cs1 += ny; cs2 += nz; cs3 += nw;
    a2 += nx*nx + ny*ny + nz*nz + nw*nw;
    float mm = (float)m[i] * inv;
    ushort4 o;
    o.x = f2bf(v[i].x * mm); o.y = f2bf(v[i].y * mm);
    o.z = f2bf(v[i].z * mm); o.w = f2bf(v[i].w * mm);
    ((ushort4*)(ddst + (size_t)(g + 8 * i) * HH))[c] = o;
  }
  *(float4*)&colsum[g * 128 + c * 4] = make_float4(cs0, cs1, cs2, cs3);

  float qa2l = 0.f;
  if (g < 4) {
    float ss = vq.x*vq.x + vq.y*vq.y + vq.z*vq.z + vq.w*vq.w;
#pragma unroll
    for (int off = 16; off; off >>= 1) ss += __shfl_xor(ss, off);
    float inv = 1.0f / fmaxf(sqrtf(ss), 1e-12f);
    float nx = vq.x * inv, ny = vq.y * inv, nz = vq.z * inv, nw = vq.w * inv;
    qa2l = nx*nx + ny*ny + nz*nz + nw*nw;
    float mm = (float)mq * inv;
    ushort4 o;
    o.x = f2bf(vq.x * mm); o.y = f2bf(vq.y * mm);
    o.z = f2bf(vq.z * mm); o.w = f2bf(vq.w * mm);
    ((ushort4*)(qng + (size_t)(bid * QCHUNK + g) * HH))[c] = o;
    *(float4*)&colsumQ[g * 128 + c * 4] = make_float4(nx, ny, nz, nw);
  }
  __syncthreads();

  // column partials -> global (unsquared; squared after full combine in k2)
  if (tid < 128) {
    float s = 0.f;
#pragma unroll
    for (int gg = 0; gg < 8; gg++) s += colsum[gg * 128 + tid];
    dcol[(size_t)bid * 128 + tid] = s;
    float sq = 0.f;
#pragma unroll
    for (int gg = 0; gg < 4; gg++) sq += colsumQ[gg * 128 + tid];
    qcol[(size_t)bid * 128 + tid] = sq;
  }
  // a2 partials (every thread counted once; q only groups 0-3 nonzero)
  float zd = a2, zq = qa2l;
#pragma unroll
  for (int off = 32; off; off >>= 1) {
    zd += __shfl_xor(zd, off);
    zq += __shfl_xor(zq, off);
  }
  if ((tid & 63) == 0) { redD[wave] = zd; redQ[wave] = zq; }
  __syncthreads();
  if (tid == 0) {
    da2[bid] = redD[0] + redD[1] + redD[2] + redD[3];
    qa2[bid] = redQ[0] + redQ[1] + redQ[2] + redQ[3];
  }
}

// ---------------------------------------------------------------------------
// Kernel 2: scores[a,b] = max_{s,t} qng[a,s]·dng[b,t] (masks pre-baked),
// PLUS fused epilogues:
//   - blocks with blockIdx.y==0 combine partials -> avgd[bb] AND avgq[bb]
//   - last-finishing block (device-scope counter) runs the CE reduction
// Grid (BB, BB/AG) = (64,8) = 512 blocks, 2 blocks/CU (LDS ~70KB).
// ---------------------------------------------------------------------------
__global__ __launch_bounds__(256, 2) void scores_kernel(
    const unsigned short* __restrict__ qng, const unsigned short* __restrict__ dng,
    float* __restrict__ scores,
    const float* __restrict__ dcol, const float* __restrict__ da2,
    const float* __restrict__ qcol, const float* __restrict__ qa2,
    float* __restrict__ avgq, float* __restrict__ avgd,
    unsigned int* __restrict__ cnt, float* __restrict__ out) {
  __shared__ __align__(16) unsigned short dt[SD][HH + 8];
  __shared__ float zredD[4], zredQ[4];
  __shared__ float sred[BB];
  __shared__ int amLast;
  const int tid = threadIdx.x;
  const int bb = blockIdx.x;
  const int m0 = blockIdx.y * AG * SQ;         // 256 q-rows per block
  const int wave = tid >> 6, lane = tid & 63;
  const int quad = lane >> 4, l16 = lane & 15;

  // stage d tile: 4096 chunks x 16B, fully coalesced (1KB per wave-instr).
#pragma unroll
  for (int i = 0; i < 16; i++) {
    int idx = i * 256 + tid;
    int row = idx >> 4, c = idx & 15;
    uint4 v = ((const uint4*)(dng + (size_t)(bb * SD + row) * HH))[c];
    *(uint4*)&dt[row][c * 8] = v;
  }

  // A fragments: wave's 64 M-rows, full K=128. 16 x short8 = 64 VGPRs.
  short8 af[4][4];
  const unsigned short* qbase = qng + (size_t)(m0 + wave * 64 + l16) * HH + quad * 8;
#pragma unroll
  for (int mi = 0; mi < 4; mi++)
#pragma unroll
    for (int kc = 0; kc < 4; kc++)
      af[mi][kc] = *(const short8*)(qbase + mi * 16 * HH + kc * 32);

  __syncthreads();

  float m0v = -1e30f, m1v = -1e30f;   // per-a maxima (a = blockIdx.y*AG + wave*2 + {0,1})
  const floatx4 zero = {0.f, 0.f, 0.f, 0.f};

#pragma unroll
  for (int nc = 0; nc < 4; nc++) {
    floatx4 acc[4][4];
#pragma unroll
    for (int mi = 0; mi < 4; mi++)
#pragma unroll
      for (int ni = 0; ni < 4; ni++) acc[mi][ni] = zero;
#pragma unroll
    for (int kc = 0; kc < 4; kc++) {
      short8 bf[4];
#pragma unroll
      for (int ni = 0; ni < 4; ni++)
        bf[ni] = *(const short8*)&dt[nc * 64 + ni * 16 + l16][kc * 32 + quad * 8];
#pragma unroll
      for (int mi = 0; mi < 4; mi++)
#pragma unroll
        for (int ni = 0; ni < 4; ni++)
          acc[mi][ni] = __builtin_amdgcn_mfma_f32_16x16x32_bf16(af[mi][kc], bf[ni], acc[mi][ni], 0, 0, 0);
    }
#pragma unroll
    for (int mi = 0; mi < 4; mi++) {
      float mm = -1e30f;
#pragma unroll
      for (int ni = 0; ni < 4; ni++)
#pragma unroll
        for (int r = 0; r < 4; r++) mm = fmaxf(mm, acc[mi][ni][r]);
      if (mi < 2) m0v = fmaxf(m0v, mm); else m1v = fmaxf(m1v, mm);
    }
  }
#pragma unroll
  for (int off = 32; off; off >>= 1) {
    m0v = fmaxf(m0v, __shfl_xor(m0v, off));
    m1v = fmaxf(m1v, __shfl_xor(m1v, off));
  }
  if (lane == 0) {
    int a = blockIdx.y * AG + wave * 2;
    scores[(size_t)a * BB + bb]       = m0v;
    scores[(size_t)(a + 1) * BB + bb] = m1v;
  }

  // -- fused epilogue: 64 designated blocks combine batch bb's partials --
  if (blockIdx.y == 0) {
    float zd = 0.f, zq = 0.f;
    if (tid < 128) {
      float sd = 0.f, sq = 0.f;
#pragma unroll
      for (int p = 0; p < PARTS; p++) {
        sd += dcol[(size_t)(bb * PARTS + p) * 128 + tid];
        sq += qcol[(size_t)(bb * PARTS + p) * 128 + tid];
      }
      zd = sd * sd; zq = sq * sq;
    }
#pragma unroll
    for (int off = 32; off; off >>= 1) {
      zd += __shfl_xor(zd, off);
      zq += __shfl_xor(zq, off);
    }
    if (lane == 0) { zredD[wave] = zd; zredQ[wave] = zq; }
    __syncthreads();
    if (tid == 0) {
      float a2d = 0.f, a2q = 0.f;
#pragma unroll
      for (int p = 0; p < PARTS; p++) {
        a2d += da2[bb * PARTS + p];
        a2q += qa2[bb * PARTS + p];
      }
      avgd[bb] = (zredD[0] + zredD[1] + zredD[2] + zredD[3] - a2d)
                 * (1.0f / ((float)SD * (float)(SD - 1)));
      avgq[bb] = (zredQ[0] + zredQ[1] + zredQ[2] + zredQ[3] - a2q)
                 * (1.0f / ((float)SQ * (float)(SQ - 1)));
    }
  }

  // -- last-block-done: release our stores, count, last block runs the CE --
  __syncthreads();
  if (tid == 0) {
    __threadfence();                       // release: scores/avg* visible device-wide
    unsigned int old = atomicAdd(cnt, 1u); // device scope by default
    amLast = (old == (unsigned int)(gridDim.x * gridDim.y - 1));
  }
  __syncthreads();
  if (!amLast) return;
  __threadfence();                         // acquire: see all other blocks' stores

  // CE: 4 threads per row a; thread j handles cols [j*16, j*16+16).
  {
    const int a = tid >> 2, j = tid & 3;
    float r[16];
    const float4* pr = (const float4*)(scores + (size_t)a * BB + j * 16);
    float mx = -1e30f;
#pragma unroll
    for (int i = 0; i < 4; i++) {
      float4 v = pr[i];
      r[i*4+0] = v.x; r[i*4+1] = v.y; r[i*4+2] = v.z; r[i*4+3] = v.w;
      mx = fmaxf(mx, fmaxf(fmaxf(v.x, v.y), fmaxf(v.z, v.w)));
    }
    mx = fmaxf(mx, __shfl_xor(mx, 1));
    mx = fmaxf(mx, __shfl_xor(mx, 2));
    float sum = 0.f;
#pragma unroll
    for (int k = 0; k < 16; k++) sum += expf(r[k] - mx);
    sum += __shfl_xor(sum, 1);
    sum += __shfl_xor(sum, 2);
    if (j == 0) {
      float diag = scores[(size_t)a * BB + a];
      sred[a] = logf(sum) + mx - diag + avgq[a] + avgd[a];
    }
    __syncthreads();
    if (tid < 64) {
      float v = sred[tid];
#pragma unroll
      for (int off = 32; off; off >>= 1) v += __shfl_xor(v, off);
      if (tid == 0) out[0] = v * (1.0f / 64.0f);
    }
  }
}

// ---------------------------------------------------------------------------
extern "C" void kernel_launch(void* const* d_in, const int* in_sizes, int n_in,
                              void* d_out, int out_size, void* d_ws, size_t ws_size,
                              hipStream_t stream) {
  const float* qe   = (const float*)d_in[0];
  const float* de   = (const float*)d_in[1];
  const int* qmask  = (const int*)d_in[2];
  const int* dmask  = (const int*)d_in[3];
  float* out = (float*)d_out;
  char* ws = (char*)d_ws;

  float* scores     = (float*)(ws);                  // 4096 f = 16384 B
  float* avgq       = (float*)(ws + 16384);          // 64 f
  float* avgd       = (float*)(ws + 16640);          // 64 f
  float* da2        = (float*)(ws + 16896);          // 512 f -> ends 18944
  float* qa2        = (float*)(ws + 18944);          // 512 f -> ends 20992
  unsigned int* cnt = (unsigned int*)(ws + 21504);   // isolated cacheline
  float* dcol       = (float*)(ws + 32768);          // 512*128 f = 262144 B
  float* qcol       = (float*)(ws + 294912);         // 512*128 f = 262144 B
  unsigned short* qng = (unsigned short*)(ws + 557056);    // 2048*128 bf16
  unsigned short* dng = (unsigned short*)(ws + 1081344);   // 16384*128 bf16

  prep_kernel<<<NBLK, 256, 0, stream>>>(qe, de, qmask, dmask, qng, dng,
                                        dcol, da2, qcol, qa2, cnt);
  scores_kernel<<<dim3(BB, BB / AG), 256, 0, stream>>>(qng, dng, scores,
                                                       dcol, da2, qcol, qa2,
                                                       avgq, avgd, cnt, out);
}

// Round 4
// 90.304 us; speedup vs baseline: 1.0277x; 1.0277x over previous
//
#include <hip/hip_runtime.h>
#include <math.h>

#define BB 64
#define SQ 32
#define SD 256
#define HH 128
#define NQ (BB*SQ)   // 2048
#define ND (BB*SD)   // 16384
#define AG 8         // a's per scores block
#define DCHUNK 32    // rows per d prep block
#define NDBLK (ND/DCHUNK)   // 512 d prep blocks
#define PARTS (SD/DCHUNK)   // 8 partials per d batch

using short8  = __attribute__((ext_vector_type(8))) short;
using floatx4 = __attribute__((ext_vector_type(4))) float;

__device__ inline unsigned short f2bf(float x) {
  union { float f; unsigned u; } c; c.f = x;
  unsigned r = c.u + 0x7fffu + ((c.u >> 16) & 1u);  // RNE
  return (unsigned short)(r >> 16);
}

// ---------------------------------------------------------------------------
// Kernel 1 (fused, re-sharded): one pass over fp32 input computing
//   - per-row inv L2 norm
//   - mask-baked normalized bf16 rows (qng = qm*q/||q||, dng likewise)
//   - pairwise-sim ingredients: column sums + sum ||n_s||^2
// Grid: 64 q blocks (full batch -> finishes avgq) + 512 d 32-row chunks
// (emit partial colsum[128] + partial a2; combined inside scores_kernel).
// Block 0 also zeroes the completion counter for kernel 2's last-block CE.
// ---------------------------------------------------------------------------
__global__ __launch_bounds__(256) void prep_kernel(
    const float* __restrict__ qe, const float* __restrict__ de,
    const int* __restrict__ qmask, const int* __restrict__ dmask,
    unsigned short* __restrict__ qng, unsigned short* __restrict__ dng,
    float* __restrict__ avgq, float* __restrict__ dcol, float* __restrict__ da2,
    unsigned int* __restrict__ cnt) {
  __shared__ float colsum[8 * 128];   // [group][col]
  __shared__ float red[4];
  const int bid = blockIdx.x, tid = threadIdx.x;
  const int g = tid >> 5, c = tid & 31;

  if (bid == 0 && tid == 0) *cnt = 0;   // re-poisoned each iter; re-arm

  const float* src; const int* msk; unsigned short* dst;
  if (bid < BB) {
    src = qe + (size_t)bid * SQ * HH; msk = qmask + bid * SQ;
    dst = qng + (size_t)bid * SQ * HH;
  } else {
    const int p = bid - BB;           // 0..511: flat 32-row chunk of d
    src = de + (size_t)p * DCHUNK * HH; msk = dmask + p * DCHUNK;
    dst = dng + (size_t)p * DCHUNK * HH;
  }

  // prefetch all 4 rows + masks (independent loads, breaks latency chains)
  float4 v[4];
#pragma unroll
  for (int i = 0; i < 4; i++)
    v[i] = ((const float4*)(src + (size_t)(g + 8 * i) * HH))[c];
  int m[4];
#pragma unroll
  for (int i = 0; i < 4; i++) m[i] = msk[g + 8 * i];

  float cs0 = 0.f, cs1 = 0.f, cs2 = 0.f, cs3 = 0.f;  // per-col partial sums
  float a2 = 0.f;                                    // partial sum ||n_s||^2
#pragma unroll
  for (int i = 0; i < 4; i++) {
    float ss = v[i].x*v[i].x + v[i].y*v[i].y + v[i].z*v[i].z + v[i].w*v[i].w;
#pragma unroll
    for (int off = 16; off; off >>= 1) ss += __shfl_xor(ss, off);  // 32-lane group
    float inv = 1.0f / fmaxf(sqrtf(ss), 1e-12f);
    float nx = v[i].x * inv, ny = v[i].y * inv, nz = v[i].z * inv, nw = v[i].w * inv;
    cs0 += nx; cs1 += ny; cs2 += nz; cs3 += nw;
    a2 += nx*nx + ny*ny + nz*nz + nw*nw;
    float mm = (float)m[i] * inv;
    ushort4 o;
    o.x = f2bf(v[i].x * mm); o.y = f2bf(v[i].y * mm);
    o.z = f2bf(v[i].z * mm); o.w = f2bf(v[i].w * mm);
    ((ushort4*)(dst + (size_t)(g + 8 * i) * HH))[c] = o;
  }
  // store col partials: contiguous float4 per lane -> conflict-free b128
  *(float4*)&colsum[g * 128 + c * 4] = make_float4(cs0, cs1, cs2, cs3);
  __syncthreads();

  if (bid < BB) {
    // full batch in-block: finish avgq = (||sum n||^2 - sum ||n||^2)/(S(S-1))
    float z = -a2;
    if (tid < 128) {
      float s = 0.f;
#pragma unroll
      for (int gg = 0; gg < 8; gg++) s += colsum[gg * 128 + tid];
      z += s * s;
    }
#pragma unroll
    for (int off = 32; off; off >>= 1) z += __shfl_xor(z, off);
    if ((tid & 63) == 0) red[tid >> 6] = z;
    __syncthreads();
    if (tid == 0)
      avgq[bid] = (red[0] + red[1] + red[2] + red[3]) * (1.0f / (SQ * (SQ - 1)));
  } else {
    // partial chunk: emit colsum vector (unsquared!) + a2 partial
    const int p = bid - BB;
    if (tid < 128) {
      float s = 0.f;
#pragma unroll
      for (int gg = 0; gg < 8; gg++) s += colsum[gg * 128 + tid];
      dcol[(size_t)p * 128 + tid] = s;
    }
    float z = a2;
#pragma unroll
    for (int off = 32; off; off >>= 1) z += __shfl_xor(z, off);
    if ((tid & 63) == 0) red[tid >> 6] = z;
    __syncthreads();
    if (tid == 0) da2[p] = red[0] + red[1] + red[2] + red[3];
  }
}

// ---------------------------------------------------------------------------
// Kernel 2: scores[a,b] = max_{s,t} qng[a,s]·dng[b,t] (masks pre-baked),
// PLUS fused epilogues:
//   - blocks with blockIdx.y==0 combine dcol/da2 partials -> avgd[bb]
//   - last-finishing block (device-scope counter) runs the CE reduction
//     and writes the final loss (replaces the old 1-block third kernel).
// Grid (BB, BB/AG) = (64,8) = 512 blocks, 2 blocks/CU (LDS ~70KB).
// ---------------------------------------------------------------------------
__global__ __launch_bounds__(256, 2) void scores_kernel(
    const unsigned short* __restrict__ qng, const unsigned short* __restrict__ dng,
    float* __restrict__ scores, const float* __restrict__ avgq,
    const float* __restrict__ dcol, const float* __restrict__ da2,
    float* __restrict__ avgd, unsigned int* __restrict__ cnt,
    float* __restrict__ out) {
  __shared__ __align__(16) unsigned short dt[SD][HH + 8];
  __shared__ float zred[4];
  __shared__ float sred[BB];
  __shared__ int amLast;
  const int tid = threadIdx.x;
  const int bb = blockIdx.x;
  const int m0 = blockIdx.y * AG * SQ;         // 256 q-rows per block
  const int wave = tid >> 6, lane = tid & 63;
  const int quad = lane >> 4, l16 = lane & 15;

  // stage d tile: 4096 chunks x 16B, fully coalesced (1KB per wave-instr).
#pragma unroll
  for (int i = 0; i < 16; i++) {
    int idx = i * 256 + tid;
    int row = idx >> 4, c = idx & 15;
    uint4 v = ((const uint4*)(dng + (size_t)(bb * SD + row) * HH))[c];
    *(uint4*)&dt[row][c * 8] = v;
  }

  // A fragments: wave's 64 M-rows, full K=128. 16 x short8 = 64 VGPRs.
  short8 af[4][4];
  const unsigned short* qbase = qng + (size_t)(m0 + wave * 64 + l16) * HH + quad * 8;
#pragma unroll
  for (int mi = 0; mi < 4; mi++)
#pragma unroll
    for (int kc = 0; kc < 4; kc++)
      af[mi][kc] = *(const short8*)(qbase + mi * 16 * HH + kc * 32);

  __syncthreads();

  float m0v = -1e30f, m1v = -1e30f;   // per-a maxima (a = blockIdx.y*AG + wave*2 + {0,1})
  const floatx4 zero = {0.f, 0.f, 0.f, 0.f};

#pragma unroll
  for (int nc = 0; nc < 4; nc++) {
    floatx4 acc[4][4];
#pragma unroll
    for (int mi = 0; mi < 4; mi++)
#pragma unroll
      for (int ni = 0; ni < 4; ni++) acc[mi][ni] = zero;
#pragma unroll
    for (int kc = 0; kc < 4; kc++) {
      short8 bf[4];
#pragma unroll
      for (int ni = 0; ni < 4; ni++)
        bf[ni] = *(const short8*)&dt[nc * 64 + ni * 16 + l16][kc * 32 + quad * 8];
#pragma unroll
      for (int mi = 0; mi < 4; mi++)
#pragma unroll
        for (int ni = 0; ni < 4; ni++)
          acc[mi][ni] = __builtin_amdgcn_mfma_f32_16x16x32_bf16(af[mi][kc], bf[ni], acc[mi][ni], 0, 0, 0);
    }
#pragma unroll
    for (int mi = 0; mi < 4; mi++) {
      float mm = -1e30f;
#pragma unroll
      for (int ni = 0; ni < 4; ni++)
#pragma unroll
        for (int r = 0; r < 4; r++) mm = fmaxf(mm, acc[mi][ni][r]);
      if (mi < 2) m0v = fmaxf(m0v, mm); else m1v = fmaxf(m1v, mm);
    }
  }
#pragma unroll
  for (int off = 32; off; off >>= 1) {
    m0v = fmaxf(m0v, __shfl_xor(m0v, off));
    m1v = fmaxf(m1v, __shfl_xor(m1v, off));
  }
  if (lane == 0) {
    int a = blockIdx.y * AG + wave * 2;
    scores[(size_t)a * BB + bb]       = m0v;
    scores[(size_t)(a + 1) * BB + bb] = m1v;
  }

  // -- fused avgd: 64 designated blocks combine their batch's dcol partials --
  if (blockIdx.y == 0) {
    float z = 0.f;
    if (tid < 128) {
      float s = 0.f;
#pragma unroll
      for (int p = 0; p < PARTS; p++) s += dcol[(size_t)(bb * PARTS + p) * 128 + tid];
      z = s * s;
    }
#pragma unroll
    for (int off = 32; off; off >>= 1) z += __shfl_xor(z, off);
    if (lane == 0) zred[wave] = z;
    __syncthreads();
    if (tid == 0) {
      float a2s = 0.f;
#pragma unroll
      for (int p = 0; p < PARTS; p++) a2s += da2[bb * PARTS + p];
      avgd[bb] = (zred[0] + zred[1] + zred[2] + zred[3] - a2s)
                 * (1.0f / ((float)SD * (float)(SD - 1)));
    }
  }

  // -- last-block-done: release our stores, count, last block runs the CE --
  __syncthreads();
  if (tid == 0) {
    __threadfence();                       // release: scores/avgd visible device-wide
    unsigned int old = atomicAdd(cnt, 1u); // device scope by default
    amLast = (old == (unsigned int)(gridDim.x * gridDim.y - 1));
  }
  __syncthreads();
  if (!amLast) return;
  __threadfence();                         // acquire: see all other blocks' stores

  // CE: 4 threads per row a; thread j handles cols [j*16, j*16+16).
  {
    const int a = tid >> 2, j = tid & 3;
    float r[16];
    const float4* pr = (const float4*)(scores + (size_t)a * BB + j * 16);
    float mx = -1e30f;
#pragma unroll
    for (int i = 0; i < 4; i++) {
      float4 v = pr[i];
      r[i*4+0] = v.x; r[i*4+1] = v.y; r[i*4+2] = v.z; r[i*4+3] = v.w;
      mx = fmaxf(mx, fmaxf(fmaxf(v.x, v.y), fmaxf(v.z, v.w)));
    }
    mx = fmaxf(mx, __shfl_xor(mx, 1));
    mx = fmaxf(mx, __shfl_xor(mx, 2));
    float sum = 0.f;
#pragma unroll
    for (int k = 0; k < 16; k++) sum += expf(r[k] - mx);
    sum += __shfl_xor(sum, 1);
    sum += __shfl_xor(sum, 2);
    if (j == 0) {
      float diag = scores[(size_t)a * BB + a];
      sred[a] = logf(sum) + mx - diag + avgq[a] + avgd[a];
    }
    __syncthreads();
    if (tid < 64) {
      float v = sred[tid];
#pragma unroll
      for (int off = 32; off; off >>= 1) v += __shfl_xor(v, off);
      if (tid == 0) out[0] = v * (1.0f / 64.0f);
    }
  }
}

// ---------------------------------------------------------------------------
extern "C" void kernel_launch(void* const* d_in, const int* in_sizes, int n_in,
                              void* d_out, int out_size, void* d_ws, size_t ws_size,
                              hipStream_t stream) {
  const float* qe   = (const float*)d_in[0];
  const float* de   = (const float*)d_in[1];
  const int* qmask  = (const int*)d_in[2];
  const int* dmask  = (const int*)d_in[3];
  float* out = (float*)d_out;
  char* ws = (char*)d_ws;

  float* scores     = (float*)(ws);                  // 4096 f = 16384 B
  float* avgq       = (float*)(ws + 16384);          // 64 f
  float* avgd       = (float*)(ws + 16640);          // 64 f
  float* da2        = (float*)(ws + 16896);          // 512 f = 2048 B -> ends 18944
  unsigned int* cnt = (unsigned int*)(ws + 19456);   // isolated cacheline
  float* dcol       = (float*)(ws + 20480);          // 512*128 f = 262144 B
  unsigned short* qng = (unsigned short*)(ws + 294912);   // 2048*128 bf16 (mask-baked)
  unsigned short* dng = (unsigned short*)(ws + 819200);   // 16384*128 bf16 (mask-baked)

  prep_kernel<<<BB + NDBLK, 256, 0, stream>>>(qe, de, qmask, dmask, qng, dng,
                                              avgq, dcol, da2, cnt);
  scores_kernel<<<dim3(BB, BB / AG), 256, 0, stream>>>(qng, dng, scores, avgq,
                                                       dcol, da2, avgd, cnt, out);
}